// Round 5
// baseline (1205.279 us; speedup 1.0000x reference)
//
#include <hip/hip_runtime.h>
#include <hip/hip_bf16.h>
#include <hip/hip_cooperative_groups.h>
#include <cstdint>

namespace cg = cooperative_groups;

#define NL 2
#define DM 768
#define DI 1536
#define DS 16
#define DD 48
#define DCONV 4
#define BB 2
#define LL 1024
#define MROWS (BB*LL)    // 2048
#define DBCW (DD + 2*DS) // 80
#define TC 32            // scan chunk length
#define NCH (LL/TC)      // 32 chunks
#define KSPL 4           // x_proj split-K ways
#define XPN 128          // x_proj padded N

typedef __bf16 bf16x8 __attribute__((ext_vector_type(8)));
typedef float f32x4 __attribute__((ext_vector_type(4)));
typedef ushort ushort8 __attribute__((ext_vector_type(8)));
using bf16 = __hip_bfloat16;

__device__ __forceinline__ float softplusf(float x) {
  return (x > 20.f) ? x : log1pf(__expf(x));
}

__device__ __forceinline__ float bfu2f(ushort u) {
  return __uint_as_float((uint32_t)u << 16);
}

__device__ __forceinline__ ushort f2bfu(float f) {
  const bf16 h = __float2bfloat16(f);
  return *reinterpret_cast<const ushort*>(&h);
}

__device__ __forceinline__ void load_lds16(const void* g, void* l) {
  __builtin_amdgcn_global_load_lds(
      (const __attribute__((address_space(1))) void*)g,
      (__attribute__((address_space(3))) void*)l, 16, 0, 0);
}

// ---------------------------------------------------------------------------
// All weight fp32->bf16 conversions in one kernel; pads x_proj N 80->128.
// ---------------------------------------------------------------------------
#define WI_N (NL*2*DI*DM)
#define WX_N (NL*XPN*DI)
#define WD_N (NL*DI*DD)
#define WO_N (NL*DM*DI)
__global__ __launch_bounds__(256)
void prep_weights(const float* __restrict__ wi, const float* __restrict__ wx,
                  const float* __restrict__ wd, const float* __restrict__ wo,
                  bf16* __restrict__ bi, bf16* __restrict__ bx,
                  bf16* __restrict__ bd, bf16* __restrict__ bo)
{
  int i = blockIdx.x * 256 + threadIdx.x;
  if (i < WI_N) { bi[i] = __float2bfloat16(wi[i]); return; }
  i -= WI_N;
  if (i < WX_N) {
    const int l = i / (XPN*DI), r = (i / DI) % XPN, k = i % DI;
    const float v = (r < DBCW) ? wx[((size_t)l*DBCW + r)*DI + k] : 0.f;
    bx[i] = __float2bfloat16(v); return;
  }
  i -= WX_N;
  if (i < WD_N) { bd[i] = __float2bfloat16(wd[i]); return; }
  i -= WD_N;
  if (i < WO_N) { bo[i] = __float2bfloat16(wo[i]); }
}

// ---------------------------------------------------------------------------
// RMSNorm: one block per row of 768, output bf16
// ---------------------------------------------------------------------------
__global__ __launch_bounds__(256)
void rmsnorm_kernel(const float* __restrict__ x, const float* __restrict__ w,
                    bf16* __restrict__ out)
{
  const int row = blockIdx.x;
  const float* xr = x + (size_t)row * DM;
  const int t = threadIdx.x;
  float v0 = xr[t], v1 = xr[t + 256], v2 = xr[t + 512];
  float ss = v0*v0 + v1*v1 + v2*v2;
  #pragma unroll
  for (int off = 32; off > 0; off >>= 1) ss += __shfl_down(ss, off);
  __shared__ float sred[4];
  if ((t & 63) == 0) sred[t >> 6] = ss;
  __syncthreads();
  const float scale = rsqrtf((sred[0]+sred[1]+sred[2]+sred[3]) * (1.f/DM) + 1e-5f);
  out[(size_t)row*DM + t      ] = __float2bfloat16(v0 * scale * w[t]);
  out[(size_t)row*DM + t + 256] = __float2bfloat16(v1 * scale * w[t + 256]);
  out[(size_t)row*DM + t + 512] = __float2bfloat16(v2 * scale * w[t + 512]);
}

// ---------------------------------------------------------------------------
// in_proj GEMM: 128x128 tile, BK=64 (two 32-wide LDS buffers per step).
// Output split: cols < DI -> bf16 xb; cols >= DI -> bf16 zb.
// ---------------------------------------------------------------------------
__global__ __launch_bounds__(256)
void gemm_in128(const bf16* __restrict__ A, const bf16* __restrict__ W,
                bf16* __restrict__ xb, bf16* __restrict__ zb)
{
  __shared__ __align__(16) bf16 As[2][128][32];
  __shared__ __align__(16) bf16 Ws[2][128][32];
  const int tid = threadIdx.x;
  const int wave = tid >> 6, lane = tid & 63;
  const int m0 = blockIdx.x * 128, n0 = blockIdx.y * 128;
  const int wr = (wave >> 1) * 64, wc = (wave & 1) * 64;
  const int l16 = lane & 15, quad = lane >> 4;
  const int srow = wave * 16 + (lane >> 2);
  const int scol = (lane & 3) * 8;

  f32x4 acc[4][4] = {};

  for (int k0 = 0; k0 < DM; k0 += 64) {
    #pragma unroll
    for (int kk = 0; kk < 2; ++kk) {
      load_lds16(A + (size_t)(m0 + srow) * DM + k0 + kk*32 + scol,      &As[kk][wave*16][0]);
      load_lds16(A + (size_t)(m0 + 64 + srow) * DM + k0 + kk*32 + scol, &As[kk][64 + wave*16][0]);
      load_lds16(W + (size_t)(n0 + srow) * DM + k0 + kk*32 + scol,      &Ws[kk][wave*16][0]);
      load_lds16(W + (size_t)(n0 + 64 + srow) * DM + k0 + kk*32 + scol, &Ws[kk][64 + wave*16][0]);
    }
    __syncthreads();

    #pragma unroll
    for (int kk = 0; kk < 2; ++kk) {
      bf16x8 af[4], wf[4];
      #pragma unroll
      for (int i = 0; i < 4; ++i)
        af[i] = *reinterpret_cast<const bf16x8*>(&As[kk][wr + i*16 + l16][quad*8]);
      #pragma unroll
      for (int j = 0; j < 4; ++j)
        wf[j] = *reinterpret_cast<const bf16x8*>(&Ws[kk][wc + j*16 + l16][quad*8]);
      #pragma unroll
      for (int i = 0; i < 4; ++i)
        #pragma unroll
        for (int j = 0; j < 4; ++j)
          acc[i][j] = __builtin_amdgcn_mfma_f32_16x16x32_bf16(af[i], wf[j], acc[i][j], 0, 0, 0);
    }
    __syncthreads();
  }

  const bool isz = (n0 >= DI);
  #pragma unroll
  for (int i = 0; i < 4; ++i) {
    #pragma unroll
    for (int j = 0; j < 4; ++j) {
      const int col = n0 + wc + j*16 + l16;
      #pragma unroll
      for (int r = 0; r < 4; ++r) {
        const int row = m0 + wr + i*16 + quad*4 + r;
        const float v = acc[i][j][r];
        if (!isz) xb[(size_t)row*DI + col]      = __float2bfloat16(v);
        else      zb[(size_t)row*DI + col - DI] = __float2bfloat16(v);
      }
    }
  }
}

// ---------------------------------------------------------------------------
// 64x64 tile GEMM, BK=64 (two 32-wide LDS buffers). K%64==0, N%64 staged.
// gridDim.z split-K partials (MODE 0) or full-K + residual add (MODE 3).
// ---------------------------------------------------------------------------
template<int MODE>
__global__ __launch_bounds__(256)
void gemm64l(const bf16* __restrict__ A, int lda,
             const bf16* __restrict__ W, int ldw,
             float* __restrict__ C, int ldc, int N, int K,
             const float* __restrict__ res)
{
  __shared__ __align__(16) bf16 As[2][64][32];
  __shared__ __align__(16) bf16 Ws[2][64][32];
  const int tid = threadIdx.x;
  const int wave = tid >> 6, lane = tid & 63;
  const int m0 = blockIdx.x * 64, n0 = blockIdx.y * 64;
  const int wr = (wave >> 1) * 32, wc = (wave & 1) * 32;
  const int l16 = lane & 15, quad = lane >> 4;
  const int srow = wave * 16 + (lane >> 2);
  const int scol = (lane & 3) * 8;

  A += (size_t)blockIdx.z * K;              // split-K column offset
  W += (size_t)blockIdx.z * K;
  C += (size_t)blockIdx.z * MROWS * ldc;    // partial-buffer offset

  f32x4 acc[2][2] = {};

  for (int k0 = 0; k0 < K; k0 += 64) {
    #pragma unroll
    for (int kk = 0; kk < 2; ++kk) {
      load_lds16(A + (size_t)(m0 + srow) * lda + k0 + kk*32 + scol, &As[kk][wave*16][0]);
      load_lds16(W + (size_t)(n0 + srow) * ldw + k0 + kk*32 + scol, &Ws[kk][wave*16][0]);
    }
    __syncthreads();
    #pragma unroll
    for (int kk = 0; kk < 2; ++kk) {
      bf16x8 af[2], wf[2];
      #pragma unroll
      for (int i = 0; i < 2; ++i)
        af[i] = *reinterpret_cast<const bf16x8*>(&As[kk][wr + i*16 + l16][quad*8]);
      #pragma unroll
      for (int j = 0; j < 2; ++j)
        wf[j] = *reinterpret_cast<const bf16x8*>(&Ws[kk][wc + j*16 + l16][quad*8]);
      #pragma unroll
      for (int i = 0; i < 2; ++i)
        #pragma unroll
        for (int j = 0; j < 2; ++j)
          acc[i][j] = __builtin_amdgcn_mfma_f32_16x16x32_bf16(af[i], wf[j], acc[i][j], 0, 0, 0);
    }
    __syncthreads();
  }

  #pragma unroll
  for (int i = 0; i < 2; ++i) {
    #pragma unroll
    for (int j = 0; j < 2; ++j) {
      const int col = n0 + wc + j*16 + l16;
      if (col >= N) continue;
      #pragma unroll
      for (int r = 0; r < 4; ++r) {
        const int row = m0 + wr + i*16 + quad*4 + r;
        float v = acc[i][j][r];
        const size_t idx = (size_t)row * ldc + col;
        if (MODE == 3) v += res[idx];
        C[idx] = v;
      }
    }
  }
}

// ---------------------------------------------------------------------------
// Causal depthwise conv (K=4) + SiLU on bf16 xb -> bf16 xob, 8 d's per thread
// ---------------------------------------------------------------------------
__global__ __launch_bounds__(256)
void conv_silu_kernel(const bf16* __restrict__ xb, const float* __restrict__ cw,
                      const float* __restrict__ cb, bf16* __restrict__ xob)
{
  const int idx = blockIdx.x * 256 + threadIdx.x;   // over MROWS*DI/8
  const int d8 = idx % (DI/8);
  const int row = idx / (DI/8);
  const int l = row % LL;
  const int d0 = d8 * 8;

  float4 cwv[8];
  #pragma unroll
  for (int j = 0; j < 8; ++j)
    cwv[j] = reinterpret_cast<const float4*>(cw)[d0 + j];

  float acc[8];
  {
    const float4* cbp = reinterpret_cast<const float4*>(cb + d0);
    float4 c0 = cbp[0], c1 = cbp[1];
    acc[0]=c0.x; acc[1]=c0.y; acc[2]=c0.z; acc[3]=c0.w;
    acc[4]=c1.x; acc[5]=c1.y; acc[6]=c1.z; acc[7]=c1.w;
  }
  #pragma unroll
  for (int k = 0; k < DCONV; ++k) {
    const int ll = l - (DCONV-1) + k;
    if (ll >= 0) {
      const ushort8 v = *reinterpret_cast<const ushort8*>(
          xb + (size_t)(row - (DCONV-1) + k) * DI + d0);
      #pragma unroll
      for (int j = 0; j < 8; ++j) {
        const float w = (k==0) ? cwv[j].x : (k==1) ? cwv[j].y : (k==2) ? cwv[j].z : cwv[j].w;
        acc[j] += w * bfu2f(v[j]);
      }
    }
  }
  ushort8 o;
  #pragma unroll
  for (int j = 0; j < 8; ++j) {
    const float s = acc[j] / (1.f + __expf(-acc[j]));
    o[j] = f2bfu(s);
  }
  *reinterpret_cast<ushort8*>(xob + (size_t)row*DI + d0) = o;
}

// ---------------------------------------------------------------------------
// dt GEMM (guarded 64x64): delta = softplus(dbc[2048x48] @ dt_w^T + b) -> bf16.
// A is reduced on the fly from the x_proj split-K partials (cols 0..47).
// ---------------------------------------------------------------------------
__global__ __launch_bounds__(256)
void gemm_dt(const float* __restrict__ xpart, const bf16* __restrict__ W,
             bf16* __restrict__ Cb, const float* __restrict__ bias)
{
  __shared__ __align__(16) bf16 As[64][40];
  __shared__ __align__(16) bf16 Ws[64][40];
  const int tid = threadIdx.x;
  const int m0 = blockIdx.x * 64, n0 = blockIdx.y * 64;
  const int wave = tid >> 6, lane = tid & 63;
  const int wr = (wave >> 1) * 32, wc = (wave & 1) * 32;
  const int l16 = lane & 15, quad = lane >> 4;
  const int srow = tid >> 2;
  const int scol = (tid & 3) * 8;

  f32x4 acc[2][2] = {};

  #pragma unroll
  for (int k0 = 0; k0 < DD; k0 += 32) {
    {
      const int cbase = k0 + scol;
      bf16* dst = &As[srow][scol];
      if (cbase < DD) {   // blocks are 8-aligned; DD=48 -> whole block valid
        float a[8] = {0,0,0,0,0,0,0,0};
        #pragma unroll
        for (int z = 0; z < KSPL; ++z) {
          const float4* p = reinterpret_cast<const float4*>(
              xpart + (size_t)z*MROWS*DBCW + (size_t)(m0 + srow)*DBCW + cbase);
          const float4 u = p[0], v = p[1];
          a[0]+=u.x; a[1]+=u.y; a[2]+=u.z; a[3]+=u.w;
          a[4]+=v.x; a[5]+=v.y; a[6]+=v.z; a[7]+=v.w;
        }
        #pragma unroll
        for (int j = 0; j < 8; ++j) dst[j] = __float2bfloat16(a[j]);
      } else {
        *reinterpret_cast<uint4*>(dst) = make_uint4(0,0,0,0);
      }
    }
    {
      const bf16* src = W + (size_t)(n0 + srow) * DD + (k0 + scol);
      bf16* dst = &Ws[srow][scol];
      if (k0 + scol + 8 <= DD) {
        *reinterpret_cast<uint4*>(dst) = *reinterpret_cast<const uint4*>(src);
      } else {
        #pragma unroll
        for (int j = 0; j < 8; ++j)
          dst[j] = (k0 + scol + j < DD) ? src[j] : __float2bfloat16(0.f);
      }
    }
    __syncthreads();
    bf16x8 af[2], wf[2];
    #pragma unroll
    for (int i = 0; i < 2; ++i)
      af[i] = *reinterpret_cast<const bf16x8*>(&As[wr + i*16 + l16][quad*8]);
    #pragma unroll
    for (int j = 0; j < 2; ++j)
      wf[j] = *reinterpret_cast<const bf16x8*>(&Ws[wc + j*16 + l16][quad*8]);
    #pragma unroll
    for (int i = 0; i < 2; ++i)
      #pragma unroll
      for (int j = 0; j < 2; ++j)
        acc[i][j] = __builtin_amdgcn_mfma_f32_16x16x32_bf16(af[i], wf[j], acc[i][j], 0, 0, 0);
    __syncthreads();
  }

  #pragma unroll
  for (int i = 0; i < 2; ++i) {
    #pragma unroll
    for (int j = 0; j < 2; ++j) {
      const int col = n0 + wc + j*16 + l16;
      #pragma unroll
      for (int r = 0; r < 4; ++r) {
        const int row = m0 + wr + i*16 + quad*4 + r;
        Cb[(size_t)row*DI + col] = __float2bfloat16(softplusf(acc[i][j][r] + bias[col]));
      }
    }
  }
}

// ---------------------------------------------------------------------------
// Cooperative fused scan: pass1 -> grid.sync -> chunk-prefix fix ->
// grid.sync -> pass2. Lane owns (b,d,chunk) and 8 of 16 n-states; partner
// lane (lane^32) the other 8. delta/x/z hoisted to registers; B/C staged in
// LDS once (live across syncs). H layout [b][c][d][n]; sdl = per-chunk sum
// of deltas (P reconstructed as exp2(An*sdl)).
// Grid = BB*NCH*(DI/128) = 768 blocks; __launch_bounds__(256,3) guarantees
// 3 blocks/CU co-residency (768 co-resident on 256 CUs).
// ---------------------------------------------------------------------------
__global__ __launch_bounds__(256, 3)
void scan_coop(const bf16* __restrict__ delta, const bf16* __restrict__ xi,
               const float* __restrict__ xpart, const float* __restrict__ A_log,
               const float* __restrict__ Dp, const bf16* __restrict__ zb,
               float* __restrict__ sdl, float* __restrict__ H,
               bf16* __restrict__ outb)
{
  cg::grid_group grid = cg::this_grid();
  __shared__ float Bs[TC][DS];
  __shared__ float Cs[TC][DS];
  const int tid = threadIdx.x;
  const int wave = tid >> 6, lane = tid & 63;
  const int s = lane >> 5;
  const int dloc = wave*32 + (lane & 31);
  const int dt = blockIdx.x % (DI/128);
  const int c  = (blockIdx.x / (DI/128)) % NCH;
  const int b  =  blockIdx.x / ((DI/128)*NCH);
  const int d  = dt*128 + dloc;
  const int t0 = c*TC;

  // stage B and C tiles [32][16] reduced from split-K partials (L2-resident)
  for (int i = tid; i < TC*2*DS; i += 256) {
    const int t = i >> 5, n32 = i & 31;
    const size_t rb = ((size_t)b*LL + t0 + t)*DBCW + DD + n32;
    float v = xpart[rb];
    #pragma unroll
    for (int z = 1; z < KSPL; ++z) v += xpart[rb + (size_t)z*(MROWS*DBCW)];
    if (n32 < DS) Bs[t][n32] = v;
    else          Cs[t][n32 - DS] = v;
  }

  // hoisted strided loads (independent, issued together); live across syncs
  const ushort* dptr = (const ushort*)(delta + ((size_t)b*LL + t0)*DI + d);
  const ushort* xptr = (const ushort*)(xi    + ((size_t)b*LL + t0)*DI + d);
  ushort dls[TC], xvs[TC];
  #pragma unroll
  for (int t = 0; t < TC; ++t) dls[t] = dptr[(size_t)t*DI];
  #pragma unroll
  for (int t = 0; t < TC; ++t) xvs[t] = xptr[(size_t)t*DI];

  float An[8];
  {
    const float4* ap = (const float4*)(A_log + (size_t)d*DS + s*8);
    float4 v0 = ap[0], v1 = ap[1];
    An[0] = -__expf(v0.x)*1.44269504f; An[1] = -__expf(v0.y)*1.44269504f;
    An[2] = -__expf(v0.z)*1.44269504f; An[3] = -__expf(v0.w)*1.44269504f;
    An[4] = -__expf(v1.x)*1.44269504f; An[5] = -__expf(v1.y)*1.44269504f;
    An[6] = -__expf(v1.z)*1.44269504f; An[7] = -__expf(v1.w)*1.44269504f;
  }
  __syncthreads();

  // ---- pass 1: chunk-local scan from h=0 ----
  {
    float h[8] = {0.f,0.f,0.f,0.f,0.f,0.f,0.f,0.f};
    float sacc = 0.f;
    #pragma unroll
    for (int t = 0; t < TC; ++t) {
      const float dl = bfu2f(dls[t]);
      const float xv = bfu2f(xvs[t]);
      const float dlxv = dl * xv;
      sacc += dl;
      const float4* brow = (const float4*)&Bs[t][s*8];
      const float4 b0 = brow[0], b1 = brow[1];
      const float bb[8] = {b0.x,b0.y,b0.z,b0.w,b1.x,b1.y,b1.z,b1.w};
      #pragma unroll
      for (int n = 0; n < 8; ++n) {
        const float dA = exp2f(dl * An[n]);
        h[n] = dA*h[n] + dlxv*bb[n];
      }
    }
    const size_t base = (((size_t)b*NCH + c)*DI + d)*DS + s*8;
    float4* Hp = (float4*)(H + base);
    Hp[0] = make_float4(h[0],h[1],h[2],h[3]);
    Hp[1] = make_float4(h[4],h[5],h[6],h[7]);
    if (s == 0) sdl[((size_t)b*NCH + c)*DI + d] = sacc;
  }

  __threadfence();
  grid.sync();

  // ---- fix: serial chunk-prefix recurrence (first 192 blocks' threads) ----
  {
    const int gid = blockIdx.x * 256 + tid;
    if (gid < BB*DI*DS) {
      const int n  = gid & 15;
      const int dd = (gid >> 4) % DI;
      const int b2 = gid / (DS * DI);
      const float An1 = -__expf(A_log[(size_t)dd*DS + n]) * 1.44269504f;
      float hin = 0.f;
      #pragma unroll 8
      for (int c2 = 0; c2 < NCH; ++c2) {
        const float Pv = exp2f(An1 * sdl[((size_t)b2*NCH + c2)*DI + dd]);
        const size_t ic = (((size_t)b2*NCH + c2)*DI + dd)*DS + n;
        const float Hv = H[ic];
        H[ic] = hin;
        hin = fmaf(Pv, hin, Hv);
      }
    }
  }

  __threadfence();
  grid.sync();

  // ---- pass 2: re-run chunk scan from prefix state, emit outputs ----
  float h[8];
  {
    const float4* hp = (const float4*)(H + (((size_t)b*NCH + c)*DI + d)*DS + s*8);
    float4 h0 = hp[0], h1 = hp[1];
    h[0]=h0.x; h[1]=h0.y; h[2]=h0.z; h[3]=h0.w;
    h[4]=h1.x; h[5]=h1.y; h[6]=h1.z; h[7]=h1.w;
  }
  const float Dd = Dp[d];
  const ushort* zptr = (const ushort*)(zb + ((size_t)b*LL + t0)*DI + d);
  ushort zvs[TC];
  #pragma unroll
  for (int t = 0; t < TC; ++t) zvs[t] = zptr[(size_t)t*DI];

  bf16* optr = outb + ((size_t)b*LL + t0)*DI + d;

  #pragma unroll
  for (int t = 0; t < TC; ++t) {
    const float dl = bfu2f(dls[t]);
    const float xv = bfu2f(xvs[t]);
    const float zv = bfu2f(zvs[t]);
    const float dlxv = dl * xv;
    const float4* brow = (const float4*)&Bs[t][s*8];
    const float4* crow = (const float4*)&Cs[t][s*8];
    const float4 b0 = brow[0], b1 = brow[1];
    const float4 c0 = crow[0], c1 = crow[1];
    const float bb[8] = {b0.x,b0.y,b0.z,b0.w,b1.x,b1.y,b1.z,b1.w};
    const float cc[8] = {c0.x,c0.y,c0.z,c0.w,c1.x,c1.y,c1.z,c1.w};
    float y = 0.f;
    #pragma unroll
    for (int n = 0; n < 8; ++n) {
      const float dA = exp2f(dl * An[n]);
      h[n] = dA*h[n] + dlxv*bb[n];
      y = fmaf(h[n], cc[n], y);
    }
    y += __shfl_xor(y, 32);
    if (s == 0) {
      const float o = (y + Dd * xv) * (zv / (1.f + __expf(-zv)));
      optr[(size_t)t*DI] = __float2bfloat16(o);
    }
  }
}

// ---------------------------------------------------------------------------
extern "C" void kernel_launch(void* const* d_in, const int* in_sizes, int n_in,
                              void* d_out, int out_size, void* d_ws, size_t ws_size,
                              hipStream_t stream)
{
  const float* x_in   = (const float*)d_in[0];
  const float* w_inp  = (const float*)d_in[1];
  const float* w_conv = (const float*)d_in[2];
  const float* b_conv = (const float*)d_in[3];
  const float* w_xprj = (const float*)d_in[4];
  const float* w_dtp  = (const float*)d_in[5];
  const float* b_dt   = (const float*)d_in[6];
  const float* a_log  = (const float*)d_in[7];
  const float* d_par  = (const float*)d_in[8];
  const float* w_outp = (const float*)d_in[9];
  const float* w_norm = (const float*)d_in[10];
  float* xfinal = (float*)d_out;

  char* ws = (char*)d_ws;
  size_t off = 0;
  auto alloc = [&](size_t bytes) -> void* {
    void* p = ws + off;
    off += (bytes + 255) & ~(size_t)255;
    return p;
  };
  bf16*  wb_in  = (bf16*) alloc((size_t)WI_N*2);
  bf16*  wb_xp  = (bf16*) alloc((size_t)WX_N*2);
  bf16*  wb_dt  = (bf16*) alloc((size_t)WD_N*2);
  bf16*  wb_out = (bf16*) alloc((size_t)WO_N*2);
  bf16*  xn     = (bf16*) alloc((size_t)MROWS*DM*2);
  bf16*  xb     = (bf16*) alloc((size_t)MROWS*DI*2);
  bf16*  zbuf   = (bf16*) alloc((size_t)MROWS*DI*2);
  bf16*  xcb    = (bf16*) alloc((size_t)MROWS*DI*2);
  float* xpart  = (float*)alloc((size_t)KSPL*MROWS*DBCW*4);
  bf16*  dltb   = (bf16*) alloc((size_t)MROWS*DI*2);
  bf16*  scb    = (bf16*) alloc((size_t)MROWS*DI*2);
  float* x1     = (float*)alloc((size_t)MROWS*DM*4);
  float* sdlw   = (float*)alloc((size_t)BB*NCH*DI*4);
  float* Hws    = (float*)alloc((size_t)BB*NCH*DI*DS*4);

  prep_weights<<<(WI_N+WX_N+WD_N+WO_N + 255)/256, 256, 0, stream>>>(
      w_inp, w_xprj, w_dtp, w_outp, wb_in, wb_xp, wb_dt, wb_out);

  const float* xprev = x_in;
  for (int l = 0; l < NL; ++l) {
    rmsnorm_kernel<<<MROWS, 256, 0, stream>>>(xprev, w_norm + l*DM, xn);

    // xz = xn @ in_proj^T : [2048, 3072], K=768; both halves bf16
    gemm_in128<<<dim3(MROWS/128, (2*DI)/128), 256, 0, stream>>>(
        xn, wb_in + (size_t)l*2*DI*DM, xb, zbuf);

    conv_silu_kernel<<<(MROWS*DI/8)/256, 256, 0, stream>>>(
        xb, w_conv + l*DI*DCONV, b_conv + l*DI, xcb);

    // dbc partials: [2048, 80], K=1536 split 4x384
    gemm64l<0><<<dim3(MROWS/64, XPN/64, KSPL), 256, 0, stream>>>(
        xcb, DI, wb_xp + (size_t)l*XPN*DI, DI, xpart, DBCW, DBCW, DI/KSPL, nullptr);

    // delta = softplus(reduce(xpart)[:, :48] @ dt_w^T + dt_b) -> bf16
    gemm_dt<<<dim3(MROWS/64, DI/64), 256, 0, stream>>>(
        xpart, wb_dt + (size_t)l*DI*DD, dltb, b_dt + l*DI);

    // fused cooperative scan (pass1 + prefix fix + pass2)
    {
      const bf16* a0 = dltb;
      const bf16* a1 = xcb;
      const float* a2 = xpart;
      const float* a3 = a_log + (size_t)l*DI*DS;
      const float* a4 = d_par + (size_t)l*DI;
      const bf16* a5 = zbuf;
      float* a6 = sdlw;
      float* a7 = Hws;
      bf16* a8 = scb;
      void* cargs[] = {(void*)&a0,(void*)&a1,(void*)&a2,(void*)&a3,(void*)&a4,
                       (void*)&a5,(void*)&a6,(void*)&a7,(void*)&a8};
      hipLaunchCooperativeKernel((void*)scan_coop,
                                 dim3(BB*NCH*(DI/128)), dim3(256),
                                 cargs, 0, stream);
    }

    // x_next = x_prev + scan_out @ out_proj^T : [2048, 768], K=1536
    float* xout = (l == NL-1) ? xfinal : x1;
    gemm64l<3><<<dim3(MROWS/64, DM/64, 1), 256, 0, stream>>>(
        scb, DI, wb_out + (size_t)l*DM*DI, DI, xout, DM, DM, DI, xprev);

    xprev = x1;
  }
}

// Round 6
// 381.495 us; speedup vs baseline: 3.1594x; 3.1594x over previous
//
#include <hip/hip_runtime.h>
#include <hip/hip_bf16.h>
#include <cstdint>

#define NL 2
#define DM 768
#define DI 1536
#define DS 16
#define DD 48
#define DCONV 4
#define BB 2
#define LL 1024
#define MROWS (BB*LL)    // 2048
#define DBCW (DD + 2*DS) // 80
#define TC 32            // scan chunk length
#define NCH (LL/TC)      // 32 chunks
#define KSPL 4           // x_proj split-K ways
#define XPN 128          // x_proj padded N

typedef __bf16 bf16x8 __attribute__((ext_vector_type(8)));
typedef float f32x4 __attribute__((ext_vector_type(4)));
typedef ushort ushort8 __attribute__((ext_vector_type(8)));
using bf16 = __hip_bfloat16;

__device__ __forceinline__ float softplusf(float x) {
  return (x > 20.f) ? x : log1pf(__expf(x));
}

__device__ __forceinline__ float bfu2f(ushort u) {
  return __uint_as_float((uint32_t)u << 16);
}

__device__ __forceinline__ ushort f2bfu(float f) {
  const bf16 h = __float2bfloat16(f);
  return *reinterpret_cast<const ushort*>(&h);
}

__device__ __forceinline__ void load_lds16(const void* g, void* l) {
  __builtin_amdgcn_global_load_lds(
      (const __attribute__((address_space(1))) void*)g,
      (__attribute__((address_space(3))) void*)l, 16, 0, 0);
}

// ---------------------------------------------------------------------------
// All weight fp32->bf16 conversions in one kernel; pads x_proj N 80->128.
// ---------------------------------------------------------------------------
#define WI_N (NL*2*DI*DM)
#define WX_N (NL*XPN*DI)
#define WD_N (NL*DI*DD)
#define WO_N (NL*DM*DI)
__global__ __launch_bounds__(256)
void prep_weights(const float* __restrict__ wi, const float* __restrict__ wx,
                  const float* __restrict__ wd, const float* __restrict__ wo,
                  bf16* __restrict__ bi, bf16* __restrict__ bx,
                  bf16* __restrict__ bd, bf16* __restrict__ bo)
{
  int i = blockIdx.x * 256 + threadIdx.x;
  if (i < WI_N) { bi[i] = __float2bfloat16(wi[i]); return; }
  i -= WI_N;
  if (i < WX_N) {
    const int l = i / (XPN*DI), r = (i / DI) % XPN, k = i % DI;
    const float v = (r < DBCW) ? wx[((size_t)l*DBCW + r)*DI + k] : 0.f;
    bx[i] = __float2bfloat16(v); return;
  }
  i -= WX_N;
  if (i < WD_N) { bd[i] = __float2bfloat16(wd[i]); return; }
  i -= WD_N;
  if (i < WO_N) { bo[i] = __float2bfloat16(wo[i]); }
}

// ---------------------------------------------------------------------------
// RMSNorm: one block per row of 768, output bf16
// ---------------------------------------------------------------------------
__global__ __launch_bounds__(256)
void rmsnorm_kernel(const float* __restrict__ x, const float* __restrict__ w,
                    bf16* __restrict__ out)
{
  const int row = blockIdx.x;
  const float* xr = x + (size_t)row * DM;
  const int t = threadIdx.x;
  float v0 = xr[t], v1 = xr[t + 256], v2 = xr[t + 512];
  float ss = v0*v0 + v1*v1 + v2*v2;
  #pragma unroll
  for (int off = 32; off > 0; off >>= 1) ss += __shfl_down(ss, off);
  __shared__ float sred[4];
  if ((t & 63) == 0) sred[t >> 6] = ss;
  __syncthreads();
  const float scale = rsqrtf((sred[0]+sred[1]+sred[2]+sred[3]) * (1.f/DM) + 1e-5f);
  out[(size_t)row*DM + t      ] = __float2bfloat16(v0 * scale * w[t]);
  out[(size_t)row*DM + t + 256] = __float2bfloat16(v1 * scale * w[t + 256]);
  out[(size_t)row*DM + t + 512] = __float2bfloat16(v2 * scale * w[t + 512]);
}

// ---------------------------------------------------------------------------
// in_proj GEMM: 128x128 tile, BK=64 (two 32-wide LDS buffers per step).
// Output split: cols < DI -> bf16 xb; cols >= DI -> bf16 zb.
// ---------------------------------------------------------------------------
__global__ __launch_bounds__(256)
void gemm_in128(const bf16* __restrict__ A, const bf16* __restrict__ W,
                bf16* __restrict__ xb, bf16* __restrict__ zb)
{
  __shared__ __align__(16) bf16 As[2][128][32];
  __shared__ __align__(16) bf16 Ws[2][128][32];
  const int tid = threadIdx.x;
  const int wave = tid >> 6, lane = tid & 63;
  const int m0 = blockIdx.x * 128, n0 = blockIdx.y * 128;
  const int wr = (wave >> 1) * 64, wc = (wave & 1) * 64;
  const int l16 = lane & 15, quad = lane >> 4;
  const int srow = wave * 16 + (lane >> 2);
  const int scol = (lane & 3) * 8;

  f32x4 acc[4][4] = {};

  for (int k0 = 0; k0 < DM; k0 += 64) {
    #pragma unroll
    for (int kk = 0; kk < 2; ++kk) {
      load_lds16(A + (size_t)(m0 + srow) * DM + k0 + kk*32 + scol,      &As[kk][wave*16][0]);
      load_lds16(A + (size_t)(m0 + 64 + srow) * DM + k0 + kk*32 + scol, &As[kk][64 + wave*16][0]);
      load_lds16(W + (size_t)(n0 + srow) * DM + k0 + kk*32 + scol,      &Ws[kk][wave*16][0]);
      load_lds16(W + (size_t)(n0 + 64 + srow) * DM + k0 + kk*32 + scol, &Ws[kk][64 + wave*16][0]);
    }
    __syncthreads();

    #pragma unroll
    for (int kk = 0; kk < 2; ++kk) {
      bf16x8 af[4], wf[4];
      #pragma unroll
      for (int i = 0; i < 4; ++i)
        af[i] = *reinterpret_cast<const bf16x8*>(&As[kk][wr + i*16 + l16][quad*8]);
      #pragma unroll
      for (int j = 0; j < 4; ++j)
        wf[j] = *reinterpret_cast<const bf16x8*>(&Ws[kk][wc + j*16 + l16][quad*8]);
      #pragma unroll
      for (int i = 0; i < 4; ++i)
        #pragma unroll
        for (int j = 0; j < 4; ++j)
          acc[i][j] = __builtin_amdgcn_mfma_f32_16x16x32_bf16(af[i], wf[j], acc[i][j], 0, 0, 0);
    }
    __syncthreads();
  }

  const bool isz = (n0 >= DI);
  #pragma unroll
  for (int i = 0; i < 4; ++i) {
    #pragma unroll
    for (int j = 0; j < 4; ++j) {
      const int col = n0 + wc + j*16 + l16;
      #pragma unroll
      for (int r = 0; r < 4; ++r) {
        const int row = m0 + wr + i*16 + quad*4 + r;
        const float v = acc[i][j][r];
        if (!isz) xb[(size_t)row*DI + col]      = __float2bfloat16(v);
        else      zb[(size_t)row*DI + col - DI] = __float2bfloat16(v);
      }
    }
  }
}

// ---------------------------------------------------------------------------
// 64x64 tile GEMM, BK=64 (two 32-wide LDS buffers). K%64==0, N%64 staged.
// gridDim.z split-K partials (MODE 0) or full-K + residual add (MODE 3).
// ---------------------------------------------------------------------------
template<int MODE>
__global__ __launch_bounds__(256)
void gemm64l(const bf16* __restrict__ A, int lda,
             const bf16* __restrict__ W, int ldw,
             float* __restrict__ C, int ldc, int N, int K,
             const float* __restrict__ res)
{
  __shared__ __align__(16) bf16 As[2][64][32];
  __shared__ __align__(16) bf16 Ws[2][64][32];
  const int tid = threadIdx.x;
  const int wave = tid >> 6, lane = tid & 63;
  const int m0 = blockIdx.x * 64, n0 = blockIdx.y * 64;
  const int wr = (wave >> 1) * 32, wc = (wave & 1) * 32;
  const int l16 = lane & 15, quad = lane >> 4;
  const int srow = wave * 16 + (lane >> 2);
  const int scol = (lane & 3) * 8;

  A += (size_t)blockIdx.z * K;              // split-K column offset
  W += (size_t)blockIdx.z * K;
  C += (size_t)blockIdx.z * MROWS * ldc;    // partial-buffer offset

  f32x4 acc[2][2] = {};

  for (int k0 = 0; k0 < K; k0 += 64) {
    #pragma unroll
    for (int kk = 0; kk < 2; ++kk) {
      load_lds16(A + (size_t)(m0 + srow) * lda + k0 + kk*32 + scol, &As[kk][wave*16][0]);
      load_lds16(W + (size_t)(n0 + srow) * ldw + k0 + kk*32 + scol, &Ws[kk][wave*16][0]);
    }
    __syncthreads();
    #pragma unroll
    for (int kk = 0; kk < 2; ++kk) {
      bf16x8 af[2], wf[2];
      #pragma unroll
      for (int i = 0; i < 2; ++i)
        af[i] = *reinterpret_cast<const bf16x8*>(&As[kk][wr + i*16 + l16][quad*8]);
      #pragma unroll
      for (int j = 0; j < 2; ++j)
        wf[j] = *reinterpret_cast<const bf16x8*>(&Ws[kk][wc + j*16 + l16][quad*8]);
      #pragma unroll
      for (int i = 0; i < 2; ++i)
        #pragma unroll
        for (int j = 0; j < 2; ++j)
          acc[i][j] = __builtin_amdgcn_mfma_f32_16x16x32_bf16(af[i], wf[j], acc[i][j], 0, 0, 0);
    }
    __syncthreads();
  }

  #pragma unroll
  for (int i = 0; i < 2; ++i) {
    #pragma unroll
    for (int j = 0; j < 2; ++j) {
      const int col = n0 + wc + j*16 + l16;
      if (col >= N) continue;
      #pragma unroll
      for (int r = 0; r < 4; ++r) {
        const int row = m0 + wr + i*16 + quad*4 + r;
        float v = acc[i][j][r];
        const size_t idx = (size_t)row * ldc + col;
        if (MODE == 3) v += res[idx];
        C[idx] = v;
      }
    }
  }
}

// ---------------------------------------------------------------------------
// Causal depthwise conv (K=4) + SiLU on bf16 xb -> bf16 xob, 8 d's per thread
// ---------------------------------------------------------------------------
__global__ __launch_bounds__(256)
void conv_silu_kernel(const bf16* __restrict__ xb, const float* __restrict__ cw,
                      const float* __restrict__ cb, bf16* __restrict__ xob)
{
  const int idx = blockIdx.x * 256 + threadIdx.x;   // over MROWS*DI/8
  const int d8 = idx % (DI/8);
  const int row = idx / (DI/8);
  const int l = row % LL;
  const int d0 = d8 * 8;

  float4 cwv[8];
  #pragma unroll
  for (int j = 0; j < 8; ++j)
    cwv[j] = reinterpret_cast<const float4*>(cw)[d0 + j];

  float acc[8];
  {
    const float4* cbp = reinterpret_cast<const float4*>(cb + d0);
    float4 c0 = cbp[0], c1 = cbp[1];
    acc[0]=c0.x; acc[1]=c0.y; acc[2]=c0.z; acc[3]=c0.w;
    acc[4]=c1.x; acc[5]=c1.y; acc[6]=c1.z; acc[7]=c1.w;
  }
  #pragma unroll
  for (int k = 0; k < DCONV; ++k) {
    const int ll = l - (DCONV-1) + k;
    if (ll >= 0) {
      const ushort8 v = *reinterpret_cast<const ushort8*>(
          xb + (size_t)(row - (DCONV-1) + k) * DI + d0);
      #pragma unroll
      for (int j = 0; j < 8; ++j) {
        const float w = (k==0) ? cwv[j].x : (k==1) ? cwv[j].y : (k==2) ? cwv[j].z : cwv[j].w;
        acc[j] += w * bfu2f(v[j]);
      }
    }
  }
  ushort8 o;
  #pragma unroll
  for (int j = 0; j < 8; ++j) {
    const float s = acc[j] / (1.f + __expf(-acc[j]));
    o[j] = f2bfu(s);
  }
  *reinterpret_cast<ushort8*>(xob + (size_t)row*DI + d0) = o;
}

// ---------------------------------------------------------------------------
// dt GEMM (guarded 64x64): delta = softplus(dbc[2048x48] @ dt_w^T + b) -> bf16.
// A is reduced on the fly from the x_proj split-K partials (cols 0..47).
// ---------------------------------------------------------------------------
__global__ __launch_bounds__(256)
void gemm_dt(const float* __restrict__ xpart, const bf16* __restrict__ W,
             bf16* __restrict__ Cb, const float* __restrict__ bias)
{
  __shared__ __align__(16) bf16 As[64][40];
  __shared__ __align__(16) bf16 Ws[64][40];
  const int tid = threadIdx.x;
  const int m0 = blockIdx.x * 64, n0 = blockIdx.y * 64;
  const int wave = tid >> 6, lane = tid & 63;
  const int wr = (wave >> 1) * 32, wc = (wave & 1) * 32;
  const int l16 = lane & 15, quad = lane >> 4;
  const int srow = tid >> 2;
  const int scol = (tid & 3) * 8;

  f32x4 acc[2][2] = {};

  #pragma unroll
  for (int k0 = 0; k0 < DD; k0 += 32) {
    {
      const int cbase = k0 + scol;
      bf16* dst = &As[srow][scol];
      if (cbase < DD) {   // blocks are 8-aligned; DD=48 -> whole block valid
        float a[8] = {0,0,0,0,0,0,0,0};
        #pragma unroll
        for (int z = 0; z < KSPL; ++z) {
          const float4* p = reinterpret_cast<const float4*>(
              xpart + (size_t)z*MROWS*DBCW + (size_t)(m0 + srow)*DBCW + cbase);
          const float4 u = p[0], v = p[1];
          a[0]+=u.x; a[1]+=u.y; a[2]+=u.z; a[3]+=u.w;
          a[4]+=v.x; a[5]+=v.y; a[6]+=v.z; a[7]+=v.w;
        }
        #pragma unroll
        for (int j = 0; j < 8; ++j) dst[j] = __float2bfloat16(a[j]);
      } else {
        *reinterpret_cast<uint4*>(dst) = make_uint4(0,0,0,0);
      }
    }
    {
      const bf16* src = W + (size_t)(n0 + srow) * DD + (k0 + scol);
      bf16* dst = &Ws[srow][scol];
      if (k0 + scol + 8 <= DD) {
        *reinterpret_cast<uint4*>(dst) = *reinterpret_cast<const uint4*>(src);
      } else {
        #pragma unroll
        for (int j = 0; j < 8; ++j)
          dst[j] = (k0 + scol + j < DD) ? src[j] : __float2bfloat16(0.f);
      }
    }
    __syncthreads();
    bf16x8 af[2], wf[2];
    #pragma unroll
    for (int i = 0; i < 2; ++i)
      af[i] = *reinterpret_cast<const bf16x8*>(&As[wr + i*16 + l16][quad*8]);
    #pragma unroll
    for (int j = 0; j < 2; ++j)
      wf[j] = *reinterpret_cast<const bf16x8*>(&Ws[wc + j*16 + l16][quad*8]);
    #pragma unroll
    for (int i = 0; i < 2; ++i)
      #pragma unroll
      for (int j = 0; j < 2; ++j)
        acc[i][j] = __builtin_amdgcn_mfma_f32_16x16x32_bf16(af[i], wf[j], acc[i][j], 0, 0, 0);
    __syncthreads();
  }

  #pragma unroll
  for (int i = 0; i < 2; ++i) {
    #pragma unroll
    for (int j = 0; j < 2; ++j) {
      const int col = n0 + wc + j*16 + l16;
      #pragma unroll
      for (int r = 0; r < 4; ++r) {
        const int row = m0 + wr + i*16 + quad*4 + r;
        Cb[(size_t)row*DI + col] = __float2bfloat16(softplusf(acc[i][j][r] + bias[col]));
      }
    }
  }
}

// ---------------------------------------------------------------------------
// Chunked parallel scan (register-state, TC=32, NCH=32). Lane owns (b,d,chunk)
// and 8 of the 16 n-states; partner lane (lane^32) the other 8. Per-t strided
// global loads hoisted to registers. B/C reduced in-block from xpart.
// pass1 stores H (chunk-local state) + sdl (sum of deltas); scan_fix
// reconstructs P = exp2(An*sdl) on the fly. H layout: [b][c][d][n].
// ---------------------------------------------------------------------------
__global__ __launch_bounds__(256)
void scan_pass1(const bf16* __restrict__ delta, const bf16* __restrict__ xi,
                const float* __restrict__ xpart, const float* __restrict__ A_log,
                float* __restrict__ sdl_out, float* __restrict__ H)
{
  __shared__ float Bs[TC][DS];
  const int tid = threadIdx.x;
  const int wave = tid >> 6, lane = tid & 63;
  const int s = lane >> 5;
  const int dloc = wave*32 + (lane & 31);
  const int dt = blockIdx.x % (DI/128);
  const int c  = (blockIdx.x / (DI/128)) % NCH;
  const int b  =  blockIdx.x / ((DI/128)*NCH);
  const int d  = dt*128 + dloc;
  const int t0 = c*TC;

  // stage B tile [32][16] reduced from split-K partials (L2-resident)
  for (int i = tid; i < TC*DS; i += 256) {
    const int t = i >> 4, n = i & 15;
    const size_t rb = ((size_t)b*LL + t0 + t)*DBCW + DD + n;
    float v = xpart[rb];
    #pragma unroll
    for (int z = 1; z < KSPL; ++z) v += xpart[rb + (size_t)z*(MROWS*DBCW)];
    Bs[t][n] = v;
  }

  // hoisted strided loads (all independent, issued together)
  const ushort* dptr = (const ushort*)(delta + ((size_t)b*LL + t0)*DI + d);
  const ushort* xptr = (const ushort*)(xi    + ((size_t)b*LL + t0)*DI + d);
  ushort dls[TC], xvs[TC];
  #pragma unroll
  for (int t = 0; t < TC; ++t) dls[t] = dptr[(size_t)t*DI];
  #pragma unroll
  for (int t = 0; t < TC; ++t) xvs[t] = xptr[(size_t)t*DI];

  float An[8];
  {
    const float4* ap = (const float4*)(A_log + (size_t)d*DS + s*8);
    float4 v0 = ap[0], v1 = ap[1];
    An[0] = -__expf(v0.x)*1.44269504f; An[1] = -__expf(v0.y)*1.44269504f;
    An[2] = -__expf(v0.z)*1.44269504f; An[3] = -__expf(v0.w)*1.44269504f;
    An[4] = -__expf(v1.x)*1.44269504f; An[5] = -__expf(v1.y)*1.44269504f;
    An[6] = -__expf(v1.z)*1.44269504f; An[7] = -__expf(v1.w)*1.44269504f;
  }
  __syncthreads();

  float h[8] = {0.f,0.f,0.f,0.f,0.f,0.f,0.f,0.f};
  float sacc = 0.f;
  #pragma unroll
  for (int t = 0; t < TC; ++t) {
    const float dl = bfu2f(dls[t]);
    const float xv = bfu2f(xvs[t]);
    const float dlxv = dl * xv;
    sacc += dl;
    const float4* brow = (const float4*)&Bs[t][s*8];
    const float4 b0 = brow[0], b1 = brow[1];
    const float bb[8] = {b0.x,b0.y,b0.z,b0.w,b1.x,b1.y,b1.z,b1.w};
    #pragma unroll
    for (int n = 0; n < 8; ++n) {
      const float dA = exp2f(dl * An[n]);
      h[n] = dA*h[n] + dlxv*bb[n];
    }
  }
  const size_t base = (((size_t)b*NCH + c)*DI + d)*DS + s*8;
  float4* Hp = (float4*)(H + base);
  Hp[0] = make_float4(h[0],h[1],h[2],h[3]);
  Hp[1] = make_float4(h[4],h[5],h[6],h[7]);
  if (s == 0) sdl_out[((size_t)b*NCH + c)*DI + d] = sacc;
}

__global__ __launch_bounds__(256)
void scan_fix(const float* __restrict__ sdl, const float* __restrict__ A_log,
              float* __restrict__ H)
{
  const int idx = blockIdx.x * 256 + threadIdx.x;   // over BB*DI*DS
  const int n = idx & 15;
  const int d = (idx >> 4) % DI;
  const int b = idx / (DS * DI);
  const float An = -__expf(A_log[(size_t)d*DS + n]) * 1.44269504f;
  float hin = 0.f;
  #pragma unroll 8
  for (int c = 0; c < NCH; ++c) {
    const float Pv = exp2f(An * sdl[((size_t)b*NCH + c)*DI + d]);
    const size_t ic = (((size_t)b*NCH + c)*DI + d)*DS + n;
    const float Hv = H[ic];
    H[ic] = hin;
    hin = fmaf(Pv, hin, Hv);
  }
}

__global__ __launch_bounds__(256)
void scan_pass2(const bf16* __restrict__ delta, const bf16* __restrict__ xi,
                const float* __restrict__ xpart, const float* __restrict__ A_log,
                const float* __restrict__ H, const float* __restrict__ Dp,
                const bf16* __restrict__ zb, bf16* __restrict__ outb)
{
  __shared__ float Bs[TC][DS];
  __shared__ float Cs[TC][DS];
  const int tid = threadIdx.x;
  const int wave = tid >> 6, lane = tid & 63;
  const int s = lane >> 5;
  const int dloc = wave*32 + (lane & 31);
  const int dt = blockIdx.x % (DI/128);
  const int c  = (blockIdx.x / (DI/128)) % NCH;
  const int b  =  blockIdx.x / ((DI/128)*NCH);
  const int d  = dt*128 + dloc;
  const int t0 = c*TC;

  // stage B and C tiles [32][16] reduced from split-K partials
  for (int i = tid; i < TC*2*DS; i += 256) {
    const int t = i >> 5, n32 = i & 31;
    const size_t rb = ((size_t)b*LL + t0 + t)*DBCW + DD + n32;
    float v = xpart[rb];
    #pragma unroll
    for (int z = 1; z < KSPL; ++z) v += xpart[rb + (size_t)z*(MROWS*DBCW)];
    if (n32 < DS) Bs[t][n32] = v;
    else          Cs[t][n32 - DS] = v;
  }

  // hoisted strided loads
  const ushort* dptr = (const ushort*)(delta + ((size_t)b*LL + t0)*DI + d);
  const ushort* xptr = (const ushort*)(xi    + ((size_t)b*LL + t0)*DI + d);
  const ushort* zptr = (const ushort*)(zb    + ((size_t)b*LL + t0)*DI + d);
  ushort dls[TC], xvs[TC], zvs[TC];
  #pragma unroll
  for (int t = 0; t < TC; ++t) dls[t] = dptr[(size_t)t*DI];
  #pragma unroll
  for (int t = 0; t < TC; ++t) xvs[t] = xptr[(size_t)t*DI];
  #pragma unroll
  for (int t = 0; t < TC; ++t) zvs[t] = zptr[(size_t)t*DI];

  float An[8];
  {
    const float4* ap = (const float4*)(A_log + (size_t)d*DS + s*8);
    float4 v0 = ap[0], v1 = ap[1];
    An[0] = -__expf(v0.x)*1.44269504f; An[1] = -__expf(v0.y)*1.44269504f;
    An[2] = -__expf(v0.z)*1.44269504f; An[3] = -__expf(v0.w)*1.44269504f;
    An[4] = -__expf(v1.x)*1.44269504f; An[5] = -__expf(v1.y)*1.44269504f;
    An[6] = -__expf(v1.z)*1.44269504f; An[7] = -__expf(v1.w)*1.44269504f;
  }
  const float Dd = Dp[d];
  float h[8];
  {
    const float4* hp = (const float4*)(H + (((size_t)b*NCH + c)*DI + d)*DS + s*8);
    float4 h0 = hp[0], h1 = hp[1];
    h[0]=h0.x; h[1]=h0.y; h[2]=h0.z; h[3]=h0.w;
    h[4]=h1.x; h[5]=h1.y; h[6]=h1.z; h[7]=h1.w;
  }
  __syncthreads();

  bf16* optr = outb + ((size_t)b*LL + t0)*DI + d;

  #pragma unroll
  for (int t = 0; t < TC; ++t) {
    const float dl = bfu2f(dls[t]);
    const float xv = bfu2f(xvs[t]);
    const float zv = bfu2f(zvs[t]);
    const float dlxv = dl * xv;
    const float4* brow = (const float4*)&Bs[t][s*8];
    const float4* crow = (const float4*)&Cs[t][s*8];
    const float4 b0 = brow[0], b1 = brow[1];
    const float4 c0 = crow[0], c1 = crow[1];
    const float bb[8] = {b0.x,b0.y,b0.z,b0.w,b1.x,b1.y,b1.z,b1.w};
    const float cc[8] = {c0.x,c0.y,c0.z,c0.w,c1.x,c1.y,c1.z,c1.w};
    float y = 0.f;
    #pragma unroll
    for (int n = 0; n < 8; ++n) {
      const float dA = exp2f(dl * An[n]);
      h[n] = dA*h[n] + dlxv*bb[n];
      y = fmaf(h[n], cc[n], y);
    }
    y += __shfl_xor(y, 32);
    if (s == 0) {
      const float o = (y + Dd * xv) * (zv / (1.f + __expf(-zv)));
      optr[(size_t)t*DI] = __float2bfloat16(o);
    }
  }
}

// ---------------------------------------------------------------------------
extern "C" void kernel_launch(void* const* d_in, const int* in_sizes, int n_in,
                              void* d_out, int out_size, void* d_ws, size_t ws_size,
                              hipStream_t stream)
{
  const float* x_in   = (const float*)d_in[0];
  const float* w_inp  = (const float*)d_in[1];
  const float* w_conv = (const float*)d_in[2];
  const float* b_conv = (const float*)d_in[3];
  const float* w_xprj = (const float*)d_in[4];
  const float* w_dtp  = (const float*)d_in[5];
  const float* b_dt   = (const float*)d_in[6];
  const float* a_log  = (const float*)d_in[7];
  const float* d_par  = (const float*)d_in[8];
  const float* w_outp = (const float*)d_in[9];
  const float* w_norm = (const float*)d_in[10];
  float* xfinal = (float*)d_out;

  char* ws = (char*)d_ws;
  size_t off = 0;
  auto alloc = [&](size_t bytes) -> void* {
    void* p = ws + off;
    off += (bytes + 255) & ~(size_t)255;
    return p;
  };
  bf16*  wb_in  = (bf16*) alloc((size_t)WI_N*2);
  bf16*  wb_xp  = (bf16*) alloc((size_t)WX_N*2);
  bf16*  wb_dt  = (bf16*) alloc((size_t)WD_N*2);
  bf16*  wb_out = (bf16*) alloc((size_t)WO_N*2);
  bf16*  xn     = (bf16*) alloc((size_t)MROWS*DM*2);
  bf16*  xb     = (bf16*) alloc((size_t)MROWS*DI*2);
  bf16*  zb     = (bf16*) alloc((size_t)MROWS*DI*2);
  bf16*  xcb    = (bf16*) alloc((size_t)MROWS*DI*2);
  float* xpart  = (float*)alloc((size_t)KSPL*MROWS*DBCW*4);
  bf16*  dltb   = (bf16*) alloc((size_t)MROWS*DI*2);
  bf16*  scb    = (bf16*) alloc((size_t)MROWS*DI*2);
  float* x1     = (float*)alloc((size_t)MROWS*DM*4);
  float* sdlw   = (float*)alloc((size_t)BB*NCH*DI*4);
  float* Hws    = (float*)alloc((size_t)BB*NCH*DI*DS*4);

  prep_weights<<<(WI_N+WX_N+WD_N+WO_N + 255)/256, 256, 0, stream>>>(
      w_inp, w_xprj, w_dtp, w_outp, wb_in, wb_xp, wb_dt, wb_out);

  const float* xprev = x_in;
  for (int l = 0; l < NL; ++l) {
    rmsnorm_kernel<<<MROWS, 256, 0, stream>>>(xprev, w_norm + l*DM, xn);

    // xz = xn @ in_proj^T : [2048, 3072], K=768; both halves bf16
    gemm_in128<<<dim3(MROWS/128, (2*DI)/128), 256, 0, stream>>>(
        xn, wb_in + (size_t)l*2*DI*DM, xb, zb);

    conv_silu_kernel<<<(MROWS*DI/8)/256, 256, 0, stream>>>(
        xb, w_conv + l*DI*DCONV, b_conv + l*DI, xcb);

    // dbc partials: [2048, 80], K=1536 split 4x384
    gemm64l<0><<<dim3(MROWS/64, XPN/64, KSPL), 256, 0, stream>>>(
        xcb, DI, wb_xp + (size_t)l*XPN*DI, DI, xpart, DBCW, DBCW, DI/KSPL, nullptr);

    // delta = softplus(reduce(xpart)[:, :48] @ dt_w^T + dt_b) -> bf16
    gemm_dt<<<dim3(MROWS/64, DI/64), 256, 0, stream>>>(
        xpart, wb_dt + (size_t)l*DI*DD, dltb, b_dt + l*DI);

    // chunked parallel scan
    scan_pass1<<<BB*NCH*(DI/128), 256, 0, stream>>>(
        dltb, xcb, xpart, a_log + (size_t)l*DI*DS, sdlw, Hws);
    scan_fix<<<(BB*DI*DS)/256, 256, 0, stream>>>(
        sdlw, a_log + (size_t)l*DI*DS, Hws);
    scan_pass2<<<BB*NCH*(DI/128), 256, 0, stream>>>(
        dltb, xcb, xpart, a_log + (size_t)l*DI*DS, Hws, d_par + l*DI, zb, scb);

    // x_next = x_prev + scan_out @ out_proj^T : [2048, 768], K=1536
    float* xout = (l == NL-1) ? xfinal : x1;
    gemm64l<3><<<dim3(MROWS/64, DM/64, 1), 256, 0, stream>>>(
        scb, DI, wb_out + (size_t)l*DM*DI, DI, xout, DM, DM, DI, xprev);

    xprev = x1;
  }
}

// Round 7
// 353.367 us; speedup vs baseline: 3.4108x; 1.0796x over previous
//
#include <hip/hip_runtime.h>
#include <hip/hip_bf16.h>
#include <cstdint>

#define NL 2
#define DM 768
#define DI 1536
#define DS 16
#define DD 48
#define DCONV 4
#define BB 2
#define LL 1024
#define MROWS (BB*LL)    // 2048
#define DBCW (DD + 2*DS) // 80
#define TC 32            // scan chunk length
#define NCH (LL/TC)      // 32 chunks
#define KSPL 4           // x_proj split-K ways
#define XPN 128          // x_proj padded N

typedef __bf16 bf16x8 __attribute__((ext_vector_type(8)));
typedef float f32x4 __attribute__((ext_vector_type(4)));
typedef ushort ushort8 __attribute__((ext_vector_type(8)));
using bf16 = __hip_bfloat16;

__device__ __forceinline__ float softplusf(float x) {
  return (x > 20.f) ? x : log1pf(__expf(x));
}

__device__ __forceinline__ float bfu2f(ushort u) {
  return __uint_as_float((uint32_t)u << 16);
}

__device__ __forceinline__ ushort f2bfu(float f) {
  const bf16 h = __float2bfloat16(f);
  return *reinterpret_cast<const ushort*>(&h);
}

__device__ __forceinline__ void load_lds16(const void* g, void* l) {
  __builtin_amdgcn_global_load_lds(
      (const __attribute__((address_space(1))) void*)g,
      (__attribute__((address_space(3))) void*)l, 16, 0, 0);
}

// ---------------------------------------------------------------------------
// All weight fp32->bf16 conversions in one kernel; pads x_proj N 80->128.
// ---------------------------------------------------------------------------
#define WI_N (NL*2*DI*DM)
#define WX_N (NL*XPN*DI)
#define WD_N (NL*DI*DD)
#define WO_N (NL*DM*DI)
__global__ __launch_bounds__(256)
void prep_weights(const float* __restrict__ wi, const float* __restrict__ wx,
                  const float* __restrict__ wd, const float* __restrict__ wo,
                  bf16* __restrict__ bi, bf16* __restrict__ bx,
                  bf16* __restrict__ bd, bf16* __restrict__ bo)
{
  int i = blockIdx.x * 256 + threadIdx.x;
  if (i < WI_N) { bi[i] = __float2bfloat16(wi[i]); return; }
  i -= WI_N;
  if (i < WX_N) {
    const int l = i / (XPN*DI), r = (i / DI) % XPN, k = i % DI;
    const float v = (r < DBCW) ? wx[((size_t)l*DBCW + r)*DI + k] : 0.f;
    bx[i] = __float2bfloat16(v); return;
  }
  i -= WX_N;
  if (i < WD_N) { bd[i] = __float2bfloat16(wd[i]); return; }
  i -= WD_N;
  if (i < WO_N) { bo[i] = __float2bfloat16(wo[i]); }
}

// ---------------------------------------------------------------------------
// RMSNorm: one block per row of 768, output bf16
// ---------------------------------------------------------------------------
__global__ __launch_bounds__(256)
void rmsnorm_kernel(const float* __restrict__ x, const float* __restrict__ w,
                    bf16* __restrict__ out)
{
  const int row = blockIdx.x;
  const float* xr = x + (size_t)row * DM;
  const int t = threadIdx.x;
  float v0 = xr[t], v1 = xr[t + 256], v2 = xr[t + 512];
  float ss = v0*v0 + v1*v1 + v2*v2;
  #pragma unroll
  for (int off = 32; off > 0; off >>= 1) ss += __shfl_down(ss, off);
  __shared__ float sred[4];
  if ((t & 63) == 0) sred[t >> 6] = ss;
  __syncthreads();
  const float scale = rsqrtf((sred[0]+sred[1]+sred[2]+sred[3]) * (1.f/DM) + 1e-5f);
  out[(size_t)row*DM + t      ] = __float2bfloat16(v0 * scale * w[t]);
  out[(size_t)row*DM + t + 256] = __float2bfloat16(v1 * scale * w[t + 256]);
  out[(size_t)row*DM + t + 512] = __float2bfloat16(v2 * scale * w[t + 512]);
}

// ---------------------------------------------------------------------------
// in_proj GEMM: 128x128 tile, BK=64 (two 32-wide LDS buffers per step).
// Output split: cols < DI -> bf16 xb; cols >= DI -> bf16 zb.
// ---------------------------------------------------------------------------
__global__ __launch_bounds__(256)
void gemm_in128(const bf16* __restrict__ A, const bf16* __restrict__ W,
                bf16* __restrict__ xb, bf16* __restrict__ zb)
{
  __shared__ __align__(16) bf16 As[2][128][32];
  __shared__ __align__(16) bf16 Ws[2][128][32];
  const int tid = threadIdx.x;
  const int wave = tid >> 6, lane = tid & 63;
  const int m0 = blockIdx.x * 128, n0 = blockIdx.y * 128;
  const int wr = (wave >> 1) * 64, wc = (wave & 1) * 64;
  const int l16 = lane & 15, quad = lane >> 4;
  const int srow = wave * 16 + (lane >> 2);
  const int scol = (lane & 3) * 8;

  f32x4 acc[4][4] = {};

  for (int k0 = 0; k0 < DM; k0 += 64) {
    #pragma unroll
    for (int kk = 0; kk < 2; ++kk) {
      load_lds16(A + (size_t)(m0 + srow) * DM + k0 + kk*32 + scol,      &As[kk][wave*16][0]);
      load_lds16(A + (size_t)(m0 + 64 + srow) * DM + k0 + kk*32 + scol, &As[kk][64 + wave*16][0]);
      load_lds16(W + (size_t)(n0 + srow) * DM + k0 + kk*32 + scol,      &Ws[kk][wave*16][0]);
      load_lds16(W + (size_t)(n0 + 64 + srow) * DM + k0 + kk*32 + scol, &Ws[kk][64 + wave*16][0]);
    }
    __syncthreads();

    #pragma unroll
    for (int kk = 0; kk < 2; ++kk) {
      bf16x8 af[4], wf[4];
      #pragma unroll
      for (int i = 0; i < 4; ++i)
        af[i] = *reinterpret_cast<const bf16x8*>(&As[kk][wr + i*16 + l16][quad*8]);
      #pragma unroll
      for (int j = 0; j < 4; ++j)
        wf[j] = *reinterpret_cast<const bf16x8*>(&Ws[kk][wc + j*16 + l16][quad*8]);
      #pragma unroll
      for (int i = 0; i < 4; ++i)
        #pragma unroll
        for (int j = 0; j < 4; ++j)
          acc[i][j] = __builtin_amdgcn_mfma_f32_16x16x32_bf16(af[i], wf[j], acc[i][j], 0, 0, 0);
    }
    __syncthreads();
  }

  const bool isz = (n0 >= DI);
  #pragma unroll
  for (int i = 0; i < 4; ++i) {
    #pragma unroll
    for (int j = 0; j < 4; ++j) {
      const int col = n0 + wc + j*16 + l16;
      #pragma unroll
      for (int r = 0; r < 4; ++r) {
        const int row = m0 + wr + i*16 + quad*4 + r;
        const float v = acc[i][j][r];
        if (!isz) xb[(size_t)row*DI + col]      = __float2bfloat16(v);
        else      zb[(size_t)row*DI + col - DI] = __float2bfloat16(v);
      }
    }
  }
}

// ---------------------------------------------------------------------------
// 64x64 tile GEMM, BK=64 (two 32-wide LDS buffers). K%64==0, N%64 staged.
// gridDim.z split-K partials (MODE 0) or full-K + residual add (MODE 3).
// ---------------------------------------------------------------------------
template<int MODE>
__global__ __launch_bounds__(256)
void gemm64l(const bf16* __restrict__ A, int lda,
             const bf16* __restrict__ W, int ldw,
             float* __restrict__ C, int ldc, int N, int K,
             const float* __restrict__ res)
{
  __shared__ __align__(16) bf16 As[2][64][32];
  __shared__ __align__(16) bf16 Ws[2][64][32];
  const int tid = threadIdx.x;
  const int wave = tid >> 6, lane = tid & 63;
  const int m0 = blockIdx.x * 64, n0 = blockIdx.y * 64;
  const int wr = (wave >> 1) * 32, wc = (wave & 1) * 32;
  const int l16 = lane & 15, quad = lane >> 4;
  const int srow = wave * 16 + (lane >> 2);
  const int scol = (lane & 3) * 8;

  A += (size_t)blockIdx.z * K;              // split-K column offset
  W += (size_t)blockIdx.z * K;
  C += (size_t)blockIdx.z * MROWS * ldc;    // partial-buffer offset

  f32x4 acc[2][2] = {};

  for (int k0 = 0; k0 < K; k0 += 64) {
    #pragma unroll
    for (int kk = 0; kk < 2; ++kk) {
      load_lds16(A + (size_t)(m0 + srow) * lda + k0 + kk*32 + scol, &As[kk][wave*16][0]);
      load_lds16(W + (size_t)(n0 + srow) * ldw + k0 + kk*32 + scol, &Ws[kk][wave*16][0]);
    }
    __syncthreads();
    #pragma unroll
    for (int kk = 0; kk < 2; ++kk) {
      bf16x8 af[2], wf[2];
      #pragma unroll
      for (int i = 0; i < 2; ++i)
        af[i] = *reinterpret_cast<const bf16x8*>(&As[kk][wr + i*16 + l16][quad*8]);
      #pragma unroll
      for (int j = 0; j < 2; ++j)
        wf[j] = *reinterpret_cast<const bf16x8*>(&Ws[kk][wc + j*16 + l16][quad*8]);
      #pragma unroll
      for (int i = 0; i < 2; ++i)
        #pragma unroll
        for (int j = 0; j < 2; ++j)
          acc[i][j] = __builtin_amdgcn_mfma_f32_16x16x32_bf16(af[i], wf[j], acc[i][j], 0, 0, 0);
    }
    __syncthreads();
  }

  #pragma unroll
  for (int i = 0; i < 2; ++i) {
    #pragma unroll
    for (int j = 0; j < 2; ++j) {
      const int col = n0 + wc + j*16 + l16;
      if (col >= N) continue;
      #pragma unroll
      for (int r = 0; r < 4; ++r) {
        const int row = m0 + wr + i*16 + quad*4 + r;
        float v = acc[i][j][r];
        const size_t idx = (size_t)row * ldc + col;
        if (MODE == 3) v += res[idx];
        C[idx] = v;
      }
    }
  }
}

// ---------------------------------------------------------------------------
// Causal depthwise conv (K=4) + SiLU on bf16 xb -> bf16 xob, 8 d's per thread
// ---------------------------------------------------------------------------
__global__ __launch_bounds__(256)
void conv_silu_kernel(const bf16* __restrict__ xb, const float* __restrict__ cw,
                      const float* __restrict__ cb, bf16* __restrict__ xob)
{
  const int idx = blockIdx.x * 256 + threadIdx.x;   // over MROWS*DI/8
  const int d8 = idx % (DI/8);
  const int row = idx / (DI/8);
  const int l = row % LL;
  const int d0 = d8 * 8;

  float4 cwv[8];
  #pragma unroll
  for (int j = 0; j < 8; ++j)
    cwv[j] = reinterpret_cast<const float4*>(cw)[d0 + j];

  float acc[8];
  {
    const float4* cbp = reinterpret_cast<const float4*>(cb + d0);
    float4 c0 = cbp[0], c1 = cbp[1];
    acc[0]=c0.x; acc[1]=c0.y; acc[2]=c0.z; acc[3]=c0.w;
    acc[4]=c1.x; acc[5]=c1.y; acc[6]=c1.z; acc[7]=c1.w;
  }
  #pragma unroll
  for (int k = 0; k < DCONV; ++k) {
    const int ll = l - (DCONV-1) + k;
    if (ll >= 0) {
      const ushort8 v = *reinterpret_cast<const ushort8*>(
          xb + (size_t)(row - (DCONV-1) + k) * DI + d0);
      #pragma unroll
      for (int j = 0; j < 8; ++j) {
        const float w = (k==0) ? cwv[j].x : (k==1) ? cwv[j].y : (k==2) ? cwv[j].z : cwv[j].w;
        acc[j] += w * bfu2f(v[j]);
      }
    }
  }
  ushort8 o;
  #pragma unroll
  for (int j = 0; j < 8; ++j) {
    const float s = acc[j] / (1.f + __expf(-acc[j]));
    o[j] = f2bfu(s);
  }
  *reinterpret_cast<ushort8*>(xob + (size_t)row*DI + d0) = o;
}

// ---------------------------------------------------------------------------
// dt GEMM (guarded 64x64): delta = softplus(dbc[2048x48] @ dt_w^T + b) -> bf16.
// A is reduced on the fly from the x_proj split-K partials (cols 0..47).
// ---------------------------------------------------------------------------
__global__ __launch_bounds__(256)
void gemm_dt(const float* __restrict__ xpart, const bf16* __restrict__ W,
             bf16* __restrict__ Cb, const float* __restrict__ bias)
{
  __shared__ __align__(16) bf16 As[64][40];
  __shared__ __align__(16) bf16 Ws[64][40];
  const int tid = threadIdx.x;
  const int m0 = blockIdx.x * 64, n0 = blockIdx.y * 64;
  const int wave = tid >> 6, lane = tid & 63;
  const int wr = (wave >> 1) * 32, wc = (wave & 1) * 32;
  const int l16 = lane & 15, quad = lane >> 4;
  const int srow = tid >> 2;
  const int scol = (tid & 3) * 8;

  f32x4 acc[2][2] = {};

  #pragma unroll
  for (int k0 = 0; k0 < DD; k0 += 32) {
    {
      const int cbase = k0 + scol;
      bf16* dst = &As[srow][scol];
      if (cbase < DD) {   // blocks are 8-aligned; DD=48 -> whole block valid
        float a[8] = {0,0,0,0,0,0,0,0};
        #pragma unroll
        for (int z = 0; z < KSPL; ++z) {
          const float4* p = reinterpret_cast<const float4*>(
              xpart + (size_t)z*MROWS*DBCW + (size_t)(m0 + srow)*DBCW + cbase);
          const float4 u = p[0], v = p[1];
          a[0]+=u.x; a[1]+=u.y; a[2]+=u.z; a[3]+=u.w;
          a[4]+=v.x; a[5]+=v.y; a[6]+=v.z; a[7]+=v.w;
        }
        #pragma unroll
        for (int j = 0; j < 8; ++j) dst[j] = __float2bfloat16(a[j]);
      } else {
        *reinterpret_cast<uint4*>(dst) = make_uint4(0,0,0,0);
      }
    }
    {
      const bf16* src = W + (size_t)(n0 + srow) * DD + (k0 + scol);
      bf16* dst = &Ws[srow][scol];
      if (k0 + scol + 8 <= DD) {
        *reinterpret_cast<uint4*>(dst) = *reinterpret_cast<const uint4*>(src);
      } else {
        #pragma unroll
        for (int j = 0; j < 8; ++j)
          dst[j] = (k0 + scol + j < DD) ? src[j] : __float2bfloat16(0.f);
      }
    }
    __syncthreads();
    bf16x8 af[2], wf[2];
    #pragma unroll
    for (int i = 0; i < 2; ++i)
      af[i] = *reinterpret_cast<const bf16x8*>(&As[wr + i*16 + l16][quad*8]);
    #pragma unroll
    for (int j = 0; j < 2; ++j)
      wf[j] = *reinterpret_cast<const bf16x8*>(&Ws[wc + j*16 + l16][quad*8]);
    #pragma unroll
    for (int i = 0; i < 2; ++i)
      #pragma unroll
      for (int j = 0; j < 2; ++j)
        acc[i][j] = __builtin_amdgcn_mfma_f32_16x16x32_bf16(af[i], wf[j], acc[i][j], 0, 0, 0);
    __syncthreads();
  }

  #pragma unroll
  for (int i = 0; i < 2; ++i) {
    #pragma unroll
    for (int j = 0; j < 2; ++j) {
      const int col = n0 + wc + j*16 + l16;
      #pragma unroll
      for (int r = 0; r < 4; ++r) {
        const int row = m0 + wr + i*16 + quad*4 + r;
        Cb[(size_t)row*DI + col] = __float2bfloat16(softplusf(acc[i][j][r] + bias[col]));
      }
    }
  }
}

// ---------------------------------------------------------------------------
// Chunked parallel scan (TC=32, NCH=32). Lane owns (b,d,chunk) and 8 of the
// 16 n-states; partner lane (lane^32) the other 8. delta/x(/z) tiles are
// staged into LDS via coalesced global_load_lds (wave w stages rows
// [8w,8w+8): 2 issues x 4 rows x 1KB). B/C reduced in-block from xpart.
// pass1 stores H + sdl; scan_fix reconstructs P = exp2(An*sdl) on the fly.
// H layout: [b][c][d][n].
// ---------------------------------------------------------------------------
__global__ __launch_bounds__(256)
void scan_pass1(const bf16* __restrict__ delta, const bf16* __restrict__ xi,
                const float* __restrict__ xpart, const float* __restrict__ A_log,
                float* __restrict__ sdl_out, float* __restrict__ H)
{
  __shared__ float Bs[TC][DS];
  __shared__ __align__(16) ushort Dl[TC][128];
  __shared__ __align__(16) ushort Xl[TC][128];
  const int tid = threadIdx.x;
  const int wave = tid >> 6, lane = tid & 63;
  const int s = lane >> 5;
  const int dloc = wave*32 + (lane & 31);
  const int dt = blockIdx.x % (DI/128);
  const int c  = (blockIdx.x / (DI/128)) % NCH;
  const int b  =  blockIdx.x / ((DI/128)*NCH);
  const int d  = dt*128 + dloc;
  const int t0 = c*TC;

  // coalesced tile staging: wave stages rows [8*wave, 8*wave+8)
  {
    const int rsub = lane >> 4;          // 0..3
    const int csub = (lane & 15) * 8;    // col element
    const size_t g0 = ((size_t)b*LL + t0 + wave*8 + rsub)*DI + dt*128 + csub;
    load_lds16(delta + g0,                 &Dl[wave*8][0]);
    load_lds16(delta + g0 + (size_t)4*DI,  &Dl[wave*8+4][0]);
    load_lds16(xi + g0,                    &Xl[wave*8][0]);
    load_lds16(xi + g0 + (size_t)4*DI,     &Xl[wave*8+4][0]);
  }

  // stage B tile [32][16] reduced from split-K partials (L2-resident)
  for (int i = tid; i < TC*DS; i += 256) {
    const int t = i >> 4, n = i & 15;
    const size_t rb = ((size_t)b*LL + t0 + t)*DBCW + DD + n;
    float v = xpart[rb];
    #pragma unroll
    for (int z = 1; z < KSPL; ++z) v += xpart[rb + (size_t)z*(MROWS*DBCW)];
    Bs[t][n] = v;
  }

  float An[8];
  {
    const float4* ap = (const float4*)(A_log + (size_t)d*DS + s*8);
    float4 v0 = ap[0], v1 = ap[1];
    An[0] = -__expf(v0.x)*1.44269504f; An[1] = -__expf(v0.y)*1.44269504f;
    An[2] = -__expf(v0.z)*1.44269504f; An[3] = -__expf(v0.w)*1.44269504f;
    An[4] = -__expf(v1.x)*1.44269504f; An[5] = -__expf(v1.y)*1.44269504f;
    An[6] = -__expf(v1.z)*1.44269504f; An[7] = -__expf(v1.w)*1.44269504f;
  }
  __syncthreads();

  float h[8] = {0.f,0.f,0.f,0.f,0.f,0.f,0.f,0.f};
  float sacc = 0.f;
  #pragma unroll
  for (int t = 0; t < TC; ++t) {
    const float dl = bfu2f(Dl[t][dloc]);
    const float xv = bfu2f(Xl[t][dloc]);
    const float dlxv = dl * xv;
    sacc += dl;
    const float4* brow = (const float4*)&Bs[t][s*8];
    const float4 b0 = brow[0], b1 = brow[1];
    const float bb[8] = {b0.x,b0.y,b0.z,b0.w,b1.x,b1.y,b1.z,b1.w};
    #pragma unroll
    for (int n = 0; n < 8; ++n) {
      const float dA = exp2f(dl * An[n]);
      h[n] = dA*h[n] + dlxv*bb[n];
    }
  }
  const size_t base = (((size_t)b*NCH + c)*DI + d)*DS + s*8;
  float4* Hp = (float4*)(H + base);
  Hp[0] = make_float4(h[0],h[1],h[2],h[3]);
  Hp[1] = make_float4(h[4],h[5],h[6],h[7]);
  if (s == 0) sdl_out[((size_t)b*NCH + c)*DI + d] = sacc;
}

__global__ __launch_bounds__(256)
void scan_fix(const float* __restrict__ sdl, const float* __restrict__ A_log,
              float* __restrict__ H)
{
  const int idx = blockIdx.x * 256 + threadIdx.x;   // over BB*DI*DS
  const int n = idx & 15;
  const int d = (idx >> 4) % DI;
  const int b = idx / (DS * DI);
  const float An = -__expf(A_log[(size_t)d*DS + n]) * 1.44269504f;
  float hin = 0.f;
  #pragma unroll 8
  for (int c = 0; c < NCH; ++c) {
    const float Pv = exp2f(An * sdl[((size_t)b*NCH + c)*DI + d]);
    const size_t ic = (((size_t)b*NCH + c)*DI + d)*DS + n;
    const float Hv = H[ic];
    H[ic] = hin;
    hin = fmaf(Pv, hin, Hv);
  }
}

__global__ __launch_bounds__(256)
void scan_pass2(const bf16* __restrict__ delta, const bf16* __restrict__ xi,
                const float* __restrict__ xpart, const float* __restrict__ A_log,
                const float* __restrict__ H, const float* __restrict__ Dp,
                const bf16* __restrict__ zb, bf16* __restrict__ outb)
{
  __shared__ float Bs[TC][DS];
  __shared__ float Cs[TC][DS];
  __shared__ __align__(16) ushort Dl[TC][128];
  __shared__ __align__(16) ushort Xl[TC][128];
  __shared__ __align__(16) ushort Zl[TC][128];
  const int tid = threadIdx.x;
  const int wave = tid >> 6, lane = tid & 63;
  const int s = lane >> 5;
  const int dloc = wave*32 + (lane & 31);
  const int dt = blockIdx.x % (DI/128);
  const int c  = (blockIdx.x / (DI/128)) % NCH;
  const int b  =  blockIdx.x / ((DI/128)*NCH);
  const int d  = dt*128 + dloc;
  const int t0 = c*TC;

  // coalesced tile staging: wave stages rows [8*wave, 8*wave+8)
  {
    const int rsub = lane >> 4;          // 0..3
    const int csub = (lane & 15) * 8;    // col element
    const size_t g0 = ((size_t)b*LL + t0 + wave*8 + rsub)*DI + dt*128 + csub;
    load_lds16(delta + g0,                 &Dl[wave*8][0]);
    load_lds16(delta + g0 + (size_t)4*DI,  &Dl[wave*8+4][0]);
    load_lds16(xi + g0,                    &Xl[wave*8][0]);
    load_lds16(xi + g0 + (size_t)4*DI,     &Xl[wave*8+4][0]);
    load_lds16(zb + g0,                    &Zl[wave*8][0]);
    load_lds16(zb + g0 + (size_t)4*DI,     &Zl[wave*8+4][0]);
  }

  // stage B and C tiles [32][16] reduced from split-K partials
  for (int i = tid; i < TC*2*DS; i += 256) {
    const int t = i >> 5, n32 = i & 31;
    const size_t rb = ((size_t)b*LL + t0 + t)*DBCW + DD + n32;
    float v = xpart[rb];
    #pragma unroll
    for (int z = 1; z < KSPL; ++z) v += xpart[rb + (size_t)z*(MROWS*DBCW)];
    if (n32 < DS) Bs[t][n32] = v;
    else          Cs[t][n32 - DS] = v;
  }

  float An[8];
  {
    const float4* ap = (const float4*)(A_log + (size_t)d*DS + s*8);
    float4 v0 = ap[0], v1 = ap[1];
    An[0] = -__expf(v0.x)*1.44269504f; An[1] = -__expf(v0.y)*1.44269504f;
    An[2] = -__expf(v0.z)*1.44269504f; An[3] = -__expf(v0.w)*1.44269504f;
    An[4] = -__expf(v1.x)*1.44269504f; An[5] = -__expf(v1.y)*1.44269504f;
    An[6] = -__expf(v1.z)*1.44269504f; An[7] = -__expf(v1.w)*1.44269504f;
  }
  const float Dd = Dp[d];
  float h[8];
  {
    const float4* hp = (const float4*)(H + (((size_t)b*NCH + c)*DI + d)*DS + s*8);
    float4 h0 = hp[0], h1 = hp[1];
    h[0]=h0.x; h[1]=h0.y; h[2]=h0.z; h[3]=h0.w;
    h[4]=h1.x; h[5]=h1.y; h[6]=h1.z; h[7]=h1.w;
  }
  __syncthreads();

  bf16* optr = outb + ((size_t)b*LL + t0)*DI + d;

  #pragma unroll
  for (int t = 0; t < TC; ++t) {
    const float dl = bfu2f(Dl[t][dloc]);
    const float xv = bfu2f(Xl[t][dloc]);
    const float zv = bfu2f(Zl[t][dloc]);
    const float dlxv = dl * xv;
    const float4* brow = (const float4*)&Bs[t][s*8];
    const float4* crow = (const float4*)&Cs[t][s*8];
    const float4 b0 = brow[0], b1 = brow[1];
    const float4 c0 = crow[0], c1 = crow[1];
    const float bb[8] = {b0.x,b0.y,b0.z,b0.w,b1.x,b1.y,b1.z,b1.w};
    const float cc[8] = {c0.x,c0.y,c0.z,c0.w,c1.x,c1.y,c1.z,c1.w};
    float y = 0.f;
    #pragma unroll
    for (int n = 0; n < 8; ++n) {
      const float dA = exp2f(dl * An[n]);
      h[n] = dA*h[n] + dlxv*bb[n];
      y = fmaf(h[n], cc[n], y);
    }
    y += __shfl_xor(y, 32);
    if (s == 0) {
      const float o = (y + Dd * xv) * (zv / (1.f + __expf(-zv)));
      optr[(size_t)t*DI] = __float2bfloat16(o);
    }
  }
}

// ---------------------------------------------------------------------------
extern "C" void kernel_launch(void* const* d_in, const int* in_sizes, int n_in,
                              void* d_out, int out_size, void* d_ws, size_t ws_size,
                              hipStream_t stream)
{
  const float* x_in   = (const float*)d_in[0];
  const float* w_inp  = (const float*)d_in[1];
  const float* w_conv = (const float*)d_in[2];
  const float* b_conv = (const float*)d_in[3];
  const float* w_xprj = (const float*)d_in[4];
  const float* w_dtp  = (const float*)d_in[5];
  const float* b_dt   = (const float*)d_in[6];
  const float* a_log  = (const float*)d_in[7];
  const float* d_par  = (const float*)d_in[8];
  const float* w_outp = (const float*)d_in[9];
  const float* w_norm = (const float*)d_in[10];
  float* xfinal = (float*)d_out;

  char* ws = (char*)d_ws;
  size_t off = 0;
  auto alloc = [&](size_t bytes) -> void* {
    void* p = ws + off;
    off += (bytes + 255) & ~(size_t)255;
    return p;
  };
  bf16*  wb_in  = (bf16*) alloc((size_t)WI_N*2);
  bf16*  wb_xp  = (bf16*) alloc((size_t)WX_N*2);
  bf16*  wb_dt  = (bf16*) alloc((size_t)WD_N*2);
  bf16*  wb_out = (bf16*) alloc((size_t)WO_N*2);
  bf16*  xn     = (bf16*) alloc((size_t)MROWS*DM*2);
  bf16*  xb     = (bf16*) alloc((size_t)MROWS*DI*2);
  bf16*  zb     = (bf16*) alloc((size_t)MROWS*DI*2);
  bf16*  xcb    = (bf16*) alloc((size_t)MROWS*DI*2);
  float* xpart  = (float*)alloc((size_t)KSPL*MROWS*DBCW*4);
  bf16*  dltb   = (bf16*) alloc((size_t)MROWS*DI*2);
  bf16*  scb    = (bf16*) alloc((size_t)MROWS*DI*2);
  float* x1     = (float*)alloc((size_t)MROWS*DM*4);
  float* sdlw   = (float*)alloc((size_t)BB*NCH*DI*4);
  float* Hws    = (float*)alloc((size_t)BB*NCH*DI*DS*4);

  prep_weights<<<(WI_N+WX_N+WD_N+WO_N + 255)/256, 256, 0, stream>>>(
      w_inp, w_xprj, w_dtp, w_outp, wb_in, wb_xp, wb_dt, wb_out);

  const float* xprev = x_in;
  for (int l = 0; l < NL; ++l) {
    rmsnorm_kernel<<<MROWS, 256, 0, stream>>>(xprev, w_norm + l*DM, xn);

    // xz = xn @ in_proj^T : [2048, 3072], K=768; both halves bf16
    gemm_in128<<<dim3(MROWS/128, (2*DI)/128), 256, 0, stream>>>(
        xn, wb_in + (size_t)l*2*DI*DM, xb, zb);

    conv_silu_kernel<<<(MROWS*DI/8)/256, 256, 0, stream>>>(
        xb, w_conv + l*DI*DCONV, b_conv + l*DI, xcb);

    // dbc partials: [2048, 80], K=1536 split 4x384
    gemm64l<0><<<dim3(MROWS/64, XPN/64, KSPL), 256, 0, stream>>>(
        xcb, DI, wb_xp + (size_t)l*XPN*DI, DI, xpart, DBCW, DBCW, DI/KSPL, nullptr);

    // delta = softplus(reduce(xpart)[:, :48] @ dt_w^T + dt_b) -> bf16
    gemm_dt<<<dim3(MROWS/64, DI/64), 256, 0, stream>>>(
        xpart, wb_dt + (size_t)l*DI*DD, dltb, b_dt + l*DI);

    // chunked parallel scan
    scan_pass1<<<BB*NCH*(DI/128), 256, 0, stream>>>(
        dltb, xcb, xpart, a_log + (size_t)l*DI*DS, sdlw, Hws);
    scan_fix<<<(BB*DI*DS)/256, 256, 0, stream>>>(
        sdlw, a_log + (size_t)l*DI*DS, Hws);
    scan_pass2<<<BB*NCH*(DI/128), 256, 0, stream>>>(
        dltb, xcb, xpart, a_log + (size_t)l*DI*DS, Hws, d_par + l*DI, zb, scb);

    // x_next = x_prev + scan_out @ out_proj^T : [2048, 768], K=1536
    float* xout = (l == NL-1) ? xfinal : x1;
    gemm64l<3><<<dim3(MROWS/64, DM/64, 1), 256, 0, stream>>>(
        scb, DI, wb_out + (size_t)l*DM*DI, DI, xout, DM, DM, DI, xprev);

    xprev = x1;
  }
}